// Round 1
// baseline (317.495 us; speedup 1.0000x reference)
//
#include <hip/hip_runtime.h>

#define N_T 8
#define N_CAPS 16
#define CAP_DIM 16
#define HW 4096
#define P_TILE 64
#define EPS 1e-6f

// Block: 256 threads, handles one (b, capsule c) pair x 64 spatial positions.
// LDS: u^2 for all 128 (t,d) channels of that capsule x 64 positions = 32 KiB.
__global__ __launch_bounds__(256) void caps_norm_kernel(
    const float* __restrict__ z, const float* __restrict__ u,
    const float* __restrict__ w, const float* __restrict__ beta,
    float* __restrict__ out)
{
    __shared__ float lds[128 * P_TILE];

    const int tid = threadIdx.x;
    const int bid = blockIdx.x;            // ((b*16 + c)*64 + ptile)
    const int ptile = bid & 63;
    const int c     = (bid >> 6) & 15;
    const int b     = bid >> 10;
    const int p0    = ptile * P_TILE;

    // uniform scalars (compiler emits s_loads)
    float W9[9];
#pragma unroll
    for (int i = 0; i < 9; ++i) W9[i] = w[i];
    const float bet = beta[0];

    const size_t base_b = (size_t)b * 2048 * HW;

    // ---- stage u^2 tile into LDS (float4, coalesced: 16 lanes per 256B row) ----
#pragma unroll
    for (int k = 0; k < 8; ++k) {
        int s = tid + k * 256;             // 0..2047 float4 slots
        int r = s >> 4;                    // row = t*16 + d, 0..127
        int q = s & 15;                    // quad within row
        int t = r >> 4, d = r & 15;
        int ch = t * 256 + c * 16 + d;
        const float4 v = *(const float4*)(u + base_b + (size_t)ch * HW + p0 + q * 4);
        float4 sq;
        sq.x = v.x * v.x; sq.y = v.y * v.y; sq.z = v.z * v.z; sq.w = v.w * v.w;
        *(float4*)(lds + r * P_TILE + q * 4) = sq;
    }
    __syncthreads();

    const float4* L = (const float4*)lds;  // [row*16 + quad]

    // ---- compute: 9-point wrapped stencil over (t,d), then (z+beta)*rsqrt ----
#pragma unroll
    for (int k = 0; k < 8; ++k) {
        int s = tid + k * 256;
        int r = s >> 4;
        int q = s & 15;
        int t = r >> 4, d = r & 15;

        float ax = 0.f, ay = 0.f, az = 0.f, aw = 0.f;
#pragma unroll
        for (int i = 0; i < 3; ++i) {
            int tt = (t + i + 7) & 7;
#pragma unroll
            for (int j = 0; j < 3; ++j) {
                int dd = (d + j + 15) & 15;
                float ww = W9[i * 3 + j];
                float4 a = L[((tt << 4) + dd) * 16 + q];
                ax += ww * a.x; ay += ww * a.y; az += ww * a.z; aw += ww * a.w;
            }
        }

        int ch = t * 256 + c * 16 + d;
        size_t gidx = base_b + (size_t)ch * HW + p0 + q * 4;
        const float4 z4 = *(const float4*)(z + gidx);
        float4 o;
        o.x = (z4.x + bet) * rsqrtf(ax + EPS);
        o.y = (z4.y + bet) * rsqrtf(ay + EPS);
        o.z = (z4.z + bet) * rsqrtf(az + EPS);
        o.w = (z4.w + bet) * rsqrtf(aw + EPS);
        *(float4*)(out + gidx) = o;
    }
}

extern "C" void kernel_launch(void* const* d_in, const int* in_sizes, int n_in,
                              void* d_out, int out_size, void* d_ws, size_t ws_size,
                              hipStream_t stream) {
    const float* z    = (const float*)d_in[0];
    const float* u    = (const float*)d_in[1];
    const float* w    = (const float*)d_in[2];
    const float* beta = (const float*)d_in[3];
    float* out = (float*)d_out;

    // grid = B(4) * N_CAPS(16) * (HW/P_TILE = 64) = 4096 blocks
    caps_norm_kernel<<<dim3(4096), dim3(256), 0, stream>>>(z, u, w, beta, out);
}